// Round 1
// baseline (605.066 us; speedup 1.0000x reference)
//
#include <hip/hip_runtime.h>
#include <math.h>
#include <stdint.h>

#define NN 50000
#define NE 200000
#define HD 768
#define TWOH 1536
#define DD1 256
#define NOUT 512
#define BM 128
#define BK 64
#define KST 12       // node GEMM k-steps (HD/BK)
#define KSTEPS 24    // fallback kernel k-steps (TWOH/BK)

typedef __bf16 bf16_t;
typedef _Float16 f16_t;
typedef __attribute__((ext_vector_type(8))) __bf16 bf16x8;
typedef __attribute__((ext_vector_type(8))) _Float16 f16x8;
typedef __attribute__((ext_vector_type(4))) float f32x4;

__device__ __forceinline__ void gl2lds16(const void* g, void* l) {
    __builtin_amdgcn_global_load_lds(
        (const __attribute__((address_space(1))) unsigned int*)g,
        (__attribute__((address_space(3))) unsigned int*)l,
        16, 0, 0);
}

// ---- W1 f32 -> bf16, pre-swizzled [nb2][ks][kc][n][8]; value = W1[n][nb2*768 + ks*64 + kc*8 + u]
__global__ void swz_w1_kernel(const float* __restrict__ w1, bf16_t* __restrict__ w1s) {
    int idx = blockIdx.x * blockDim.x + threadIdx.x;   // 0 .. 2*12*8*256
    if (idx >= 2 * KST * 8 * 256) return;
    int n   = idx & 255;
    int kc  = (idx >> 8) & 7;
    int ksn = idx >> 11;                 // 0..23
    int nb2 = (ksn >= KST) ? 1 : 0;
    int ks  = ksn - nb2 * KST;
    const float* gp = w1 + (size_t)n * TWOH + nb2 * HD + ks * BK + kc * 8;
    float4 v0 = ((const float4*)gp)[0];
    float4 v1 = ((const float4*)gp)[1];
    bf16x8 o;
    o[0]=(bf16_t)v0.x; o[1]=(bf16_t)v0.y; o[2]=(bf16_t)v0.z; o[3]=(bf16_t)v0.w;
    o[4]=(bf16_t)v1.x; o[5]=(bf16_t)v1.y; o[6]=(bf16_t)v1.z; o[7]=(bf16_t)v1.w;
    *(bf16x8*)(w1s + (size_t)idx * 8) = o;
}

__global__ void finalize_kernel(float* __restrict__ out, const float* __restrict__ accum) {
    out[0] = accum[0] / accum[1];
}

// ---- node projection GEMM: h[n][0:256] = x[n] @ W1a^T ; h[n][256:512] = x[n] @ W1b^T (no bias/gelu)
__global__ __launch_bounds__(512, 4)
void node_gemm(const float* __restrict__ x, const bf16_t* __restrict__ w1s,
               f16_t* __restrict__ h)
{
    // LDS: A0[128m][64k] 16KB @0 | A1 16KB @16384 | B[8kc][256n][8] 32KB @32768 = 64KB
    __shared__ __align__(16) char smem[65536];

    const int t = threadIdx.x;
    const int lane = t & 63;
    const int wv = t >> 6;
    const int wm = wv & 1;
    const int wn = wv >> 1;
    const int q = lane >> 4;
    const int r = lane & 15;

    // bijective XCD-chunked swizzle so the (nb2=0, nb2=1) pair of each m-tile
    // lands on the same XCD -> second x-read is an L2 hit.
    const int nwg = ((NN + BM - 1) / BM) * 2;   // 782
    const int qq = nwg >> 3, rr8 = nwg & 7;
    int bid = blockIdx.x;
    int xcd = bid & 7, ii = bid >> 3;
    int wg = (xcd < rr8 ? xcd * (qq + 1) : rr8 * (qq + 1) + (xcd - rr8) * qq) + ii;
    const int mtile = wg >> 1;
    const int nb2 = wg & 1;

    const int r0 = t >> 3;                    // staging rows r0, r0+64
    const int gsl = (t & 7) ^ (r0 & 7);       // xor-swizzled global chunk
    int grow0 = mtile * BM + r0;       if (grow0 >= NN) grow0 = 0;
    int grow1 = mtile * BM + r0 + 64;  if (grow1 >= NN) grow1 = 0;
    const float* gA0 = x + (size_t)grow0 * HD + gsl * 8;
    const float* gA1 = x + (size_t)grow1 * HD + gsl * 8;

    f32x4 acc[4][4];
    #pragma unroll
    for (int a_ = 0; a_ < 4; ++a_)
        #pragma unroll
        for (int b_ = 0; b_ < 4; ++b_) acc[a_][b_] = (f32x4){0.f, 0.f, 0.f, 0.f};

    float4 pr[4];
    auto loadA = [&](int ks) {
        const float4* p0 = (const float4*)(gA0 + ks * BK);
        const float4* p1 = (const float4*)(gA1 + ks * BK);
        pr[0] = p0[0]; pr[1] = p0[1];
        pr[2] = p1[0]; pr[3] = p1[1];
    };
    auto writeA = [&](char* Ab) {
        bf16x8 o0, o1;
        o0[0]=(bf16_t)pr[0].x; o0[1]=(bf16_t)pr[0].y; o0[2]=(bf16_t)pr[0].z; o0[3]=(bf16_t)pr[0].w;
        o0[4]=(bf16_t)pr[1].x; o0[5]=(bf16_t)pr[1].y; o0[6]=(bf16_t)pr[1].z; o0[7]=(bf16_t)pr[1].w;
        o1[0]=(bf16_t)pr[2].x; o1[1]=(bf16_t)pr[2].y; o1[2]=(bf16_t)pr[2].z; o1[3]=(bf16_t)pr[2].w;
        o1[4]=(bf16_t)pr[3].x; o1[5]=(bf16_t)pr[3].y; o1[6]=(bf16_t)pr[3].z; o1[7]=(bf16_t)pr[3].w;
        *(bf16x8*)((bf16_t*)Ab + t * 8) = o0;          // row r0,    slot t&7
        *(bf16x8*)((bf16_t*)Ab + 4096 + t * 8) = o1;   // row r0+64, slot t&7
    };

    // prologue: A(0) -> buf0
    loadA(0);
    writeA(smem);

    for (int ks = 0; ks < KST; ++ks) {
        bf16_t* Ac = (bf16_t*)(smem + ((ks & 1) << 14));
        char*   An = smem + ((~ks & 1) << 14);
        bf16_t* Bl = (bf16_t*)(smem + 32768);

        __syncthreads();   // B1: A(ks) ds_writes visible; prev-step LDS reads done

        // stage B(ks) for this n-half: 4 gl2lds/thread, lane-linear, coalesced
        #pragma unroll
        for (int i = 0; i < 4; ++i) {
            const int ci = i * 512 + t;
            gl2lds16(w1s + (size_t)(nb2 * KST + ks) * 16384 + (size_t)ci * 8, Bl + ci * 8);
        }
        __builtin_amdgcn_sched_barrier(0);

        // issue A(ks+1) f32 loads now; ds_write happens AFTER the MFMA phase (T14 split)
        const bool pf = (ks + 1 < KST);
        if (pf) loadA(ks + 1);
        __builtin_amdgcn_sched_barrier(0);

        // B2: wait only the 4 B gl2lds (A loads stay in flight under the MFMA phase)
        if (pf) asm volatile("s_waitcnt vmcnt(4)\n\ts_barrier" ::: "memory");
        else    asm volatile("s_waitcnt vmcnt(0)\n\ts_barrier" ::: "memory");

        #pragma unroll
        for (int kk = 0; kk < 2; ++kk) {
            bf16x8 af[4];
            const int sl = (kk * 4 + q) ^ (r & 7);
            #pragma unroll
            for (int mb = 0; mb < 4; ++mb)
                af[mb] = *(const bf16x8*)(Ac + (wm * 64 + mb * 16 + r) * 64 + sl * 8);
            #pragma unroll
            for (int nb = 0; nb < 4; ++nb) {
                bf16x8 bfr = *(const bf16x8*)(Bl + (size_t)(((kk * 4 + q) << 8) + wn * 64 + nb * 16 + r) * 8);
                #pragma unroll
                for (int mb = 0; mb < 4; ++mb)
                    acc[mb][nb] = __builtin_amdgcn_mfma_f32_16x16x32_bf16(af[mb], bfr, acc[mb][nb], 0, 0, 0);
            }
        }
        __builtin_amdgcn_sched_barrier(0);

        if (pf) writeA(An);   // waits its own vmcnt, then 2 ds_write_b128
    }

    // epilogue: store raw projections as f16
    #pragma unroll
    for (int mb = 0; mb < 4; ++mb) {
        #pragma unroll
        for (int rr2 = 0; rr2 < 4; ++rr2) {
            const int row = wm * 64 + mb * 16 + q * 4 + rr2;
            const int grow = mtile * BM + row;
            if (grow < NN) {
                f16_t* hp = h + (size_t)grow * NOUT + nb2 * DD1 + wn * 64 + r;
                #pragma unroll
                for (int nb = 0; nb < 4; ++nb)
                    hp[nb * 16] = (f16_t)acc[mb][nb][rr2];
            }
        }
    }
}

// ---- edge pass: gather P[src] + Q[dst] -> gelu -> 256x2 linear -> softmax/CE
__global__ __launch_bounds__(512, 4)
void edge_mlp2(const f16_t* __restrict__ h, const float* __restrict__ b1,
               const float* __restrict__ w2, const float* __restrict__ b2,
               const float* __restrict__ cw, const int* __restrict__ esrc,
               const int* __restrict__ edst, const int* __restrict__ lab,
               float* __restrict__ out, float* __restrict__ accum)
{
    __shared__ float red[16];
    const int t = threadIdx.x;
    const int lane = t & 63;
    const int wv = t >> 6;
    const int sl = lane & 31;                      // 32 lanes per edge, 8 cols each
    const int e = blockIdx.x * 16 + wv * 2 + (lane >> 5);   // NE = 12500*16 exactly
    const int src = esrc[e];
    const int dst = edst[e];
    const int c0 = sl * 8;

    f16x8 ha = *(const f16x8*)(h + (size_t)src * NOUT + c0);
    f16x8 hb = *(const f16x8*)(h + (size_t)dst * NOUT + DD1 + c0);
    float4 b1a = *(const float4*)(b1 + c0);
    float4 b1b = *(const float4*)(b1 + c0 + 4);
    float4 wa0 = *(const float4*)(w2 + c0);
    float4 wa1 = *(const float4*)(w2 + c0 + 4);
    float4 wb0 = *(const float4*)(w2 + DD1 + c0);
    float4 wb1 = *(const float4*)(w2 + DD1 + c0 + 4);

    const float bb[8]  = {b1a.x,b1a.y,b1a.z,b1a.w,b1b.x,b1b.y,b1b.z,b1b.w};
    const float w0v[8] = {wa0.x,wa0.y,wa0.z,wa0.w,wa1.x,wa1.y,wa1.z,wa1.w};
    const float w1v[8] = {wb0.x,wb0.y,wb0.z,wb0.w,wb1.x,wb1.y,wb1.z,wb1.w};

    float l0 = 0.f, l1 = 0.f;
    #pragma unroll
    for (int u = 0; u < 8; ++u) {
        float v = (float)ha[u] + (float)hb[u] + bb[u];
        float g = 0.5f * v * (1.f + erff(v * 0.70710678118654752f));
        l0 += g * w0v[u];
        l1 += g * w1v[u];
    }
    #pragma unroll
    for (int o = 1; o < 32; o <<= 1) {
        l0 += __shfl_xor(l0, o);
        l1 += __shfl_xor(l1, o);
    }

    float wnll_t = 0.f, wsum_t = 0.f;
    if (sl == 0) {
        float L0 = l0 + b2[0], L1 = l1 + b2[1];
        float mx = fmaxf(L0, L1);
        float e0 = expf(L0 - mx), e1 = expf(L1 - mx);
        float s = e0 + e1, inv = 1.f / s;
        out[1 + 2 * e] = e0 * inv;
        out[2 + 2 * e] = e1 * inv;
        int lb = lab[e];
        float w = cw[lb];
        wnll_t = w * (mx + logf(s) - (lb ? L1 : L0));
        wsum_t = w;
    }
    wnll_t += __shfl_xor(wnll_t, 32);
    wsum_t += __shfl_xor(wsum_t, 32);
    if (lane == 0) { red[wv] = wnll_t; red[8 + wv] = wsum_t; }
    __syncthreads();
    if (t == 0) {
        float a_ = 0.f, b_ = 0.f;
        #pragma unroll
        for (int i = 0; i < 8; ++i) { a_ += red[i]; b_ += red[8 + i]; }
        atomicAdd(&accum[0], a_);
        atomicAdd(&accum[1], b_);
    }
}

// ================== safety fallback: previous proven fused kernel ==================
template<bool XPRE, bool WPRE>
__global__ __launch_bounds__(512, 4)
void fused_edge_mlp(const float* __restrict__ xf, const bf16_t* __restrict__ xb,
                    const float* __restrict__ w1f, const bf16_t* __restrict__ w1s,
                    const float* __restrict__ b1, const float* __restrict__ w2,
                    const float* __restrict__ b2, const float* __restrict__ cw,
                    const int* __restrict__ esrc, const int* __restrict__ edst,
                    const int* __restrict__ lab, float* __restrict__ out,
                    float* __restrict__ accum)
{
    __shared__ __align__(16) char smem[65536];
    const int t = threadIdx.x;
    const int lane = t & 63;
    const int wv = t >> 6;
    const int wm = wv & 1;
    const int wn = wv >> 1;
    const int q = lane >> 4;
    const int r = lane & 15;
    const int ebase = blockIdx.x * BM;
    const int r0 = t >> 3;
    const int e1c = (ebase + r0 + 64 < NE) ? (ebase + r0 + 64) : 0;
    const int ns0 = esrc[ebase + r0];
    const int nd0 = edst[ebase + r0];
    const int ns1 = esrc[e1c];
    const int nd1 = edst[e1c];
    const int gsl = (t & 7) ^ (r0 & 7);

    f32x4 acc[4][4];
    #pragma unroll
    for (int a_ = 0; a_ < 4; ++a_)
        #pragma unroll
        for (int b_ = 0; b_ < 4; ++b_) acc[a_][b_] = (f32x4){0.f, 0.f, 0.f, 0.f};

    auto stageA = [&](int kp, char* AbBase) {
        const bool issrc = (kp < 12);
        const int col0 = issrc ? kp * BK : kp * BK - HD;
        #pragma unroll
        for (int i = 0; i < 2; ++i) {
            const int node = i ? (issrc ? ns1 : nd1) : (issrc ? ns0 : nd0);
            bf16_t* lp = (bf16_t*)AbBase + i * 4096 + t * 8;
            if (XPRE) {
                gl2lds16(xb + (size_t)node * HD + col0 + gsl * 8, lp);
            } else {
                const float* gp = xf + (size_t)node * HD + col0 + gsl * 8;
                float4 v0 = ((const float4*)gp)[0];
                float4 v1 = ((const float4*)gp)[1];
                bf16x8 o;
                o[0]=(bf16_t)v0.x; o[1]=(bf16_t)v0.y; o[2]=(bf16_t)v0.z; o[3]=(bf16_t)v0.w;
                o[4]=(bf16_t)v1.x; o[5]=(bf16_t)v1.y; o[6]=(bf16_t)v1.z; o[7]=(bf16_t)v1.w;
                *(bf16x8*)lp = o;
            }
        }
    };

    stageA(0, smem);

    for (int ks = 0; ks < KSTEPS; ++ks) {
        bf16_t* Ac = (bf16_t*)(smem + ((ks & 1) << 14));
        char*   An = smem + ((~ks & 1) << 14);
        bf16_t* Bl = (bf16_t*)(smem + 32768);
        __syncthreads();
        #pragma unroll
        for (int i = 0; i < 4; ++i) {
            const int ci = i * 512 + t;
            bf16_t* lp = Bl + ci * 8;
            if (WPRE) {
                gl2lds16(w1s + (size_t)ks * 16384 + ci * 8, lp);
            } else {
                const int n = ci & 255, kc = ci >> 8;
                const float* gp = w1f + (size_t)n * TWOH + ks * BK + kc * 8;
                float4 v0 = ((const float4*)gp)[0];
                float4 v1 = ((const float4*)gp)[1];
                bf16x8 o;
                o[0]=(bf16_t)v0.x; o[1]=(bf16_t)v0.y; o[2]=(bf16_t)v0.z; o[3]=(bf16_t)v0.w;
                o[4]=(bf16_t)v1.x; o[5]=(bf16_t)v1.y; o[6]=(bf16_t)v1.z; o[7]=(bf16_t)v1.w;
                *(bf16x8*)lp = o;
            }
        }
        if (XPRE && WPRE)
            asm volatile("s_waitcnt vmcnt(0)\n\ts_barrier" ::: "memory");
        else
            __syncthreads();
        if (ks + 1 < KSTEPS) stageA(ks + 1, An);
        #pragma unroll
        for (int kk = 0; kk < 2; ++kk) {
            bf16x8 af[4];
            const int sl = (kk * 4 + q) ^ (r & 7);
            #pragma unroll
            for (int mb = 0; mb < 4; ++mb) {
                const int m = wm * 64 + mb * 16 + r;
                af[mb] = *(const bf16x8*)(Ac + m * 64 + sl * 8);
            }
            #pragma unroll
            for (int nb = 0; nb < 4; ++nb) {
                bf16x8 bfr = *(const bf16x8*)(Bl + (size_t)(((kk * 4 + q) << 8) + wn * 64 + nb * 16 + r) * 8);
                #pragma unroll
                for (int mb = 0; mb < 4; ++mb)
                    acc[mb][nb] = __builtin_amdgcn_mfma_f32_16x16x32_bf16(af[mb], bfr, acc[mb][nb], 0, 0, 0);
            }
        }
    }

    bf16_t* Hl = (bf16_t*)smem;
    float* red = (float*)(smem + 32768);
    float bias[4];
    #pragma unroll
    for (int nb = 0; nb < 4; ++nb) bias[nb] = b1[wn * 64 + nb * 16 + r];

    float wnll_t = 0.f, wsum_t = 0.f;
    const int ml2 = t >> 3;
    const int p = t & 7;

    #pragma unroll
    for (int half = 0; half < 2; ++half) {
        __syncthreads();
        if (wm == half) {
            #pragma unroll
            for (int mb = 0; mb < 4; ++mb)
                #pragma unroll
                for (int nb = 0; nb < 4; ++nb)
                    #pragma unroll
                    for (int rr = 0; rr < 4; ++rr) {
                        int ml = mb * 16 + q * 4 + rr;
                        int col = wn * 64 + nb * 16 + r;
                        float v = acc[mb][nb][rr] + bias[nb];
                        float g = 0.5f * v * (1.f + erff(v * 0.70710678118654752f));
                        int swcol = ((((col >> 3) ^ (ml & 7)) << 3) | (col & 7));
                        Hl[ml * 256 + swcol] = (bf16_t)g;
                    }
        }
        __syncthreads();
        float l0 = 0.f, l1 = 0.f;
        #pragma unroll
        for (int j = 0; j < 4; ++j) {
            int cj = p * 4 + j;
            bf16x8 hv = *(const bf16x8*)(Hl + ml2 * 256 + ((cj ^ (ml2 & 7)) << 3));
            const float4* w2a = (const float4*)(w2 + cj * 8);
            const float4* w2b = (const float4*)(w2 + 256 + cj * 8);
            float4 wa0 = w2a[0], wa1 = w2a[1], wb0 = w2b[0], wb1 = w2b[1];
            float hf[8];
            #pragma unroll
            for (int u = 0; u < 8; ++u) hf[u] = (float)hv[u];
            l0 += hf[0]*wa0.x + hf[1]*wa0.y + hf[2]*wa0.z + hf[3]*wa0.w
                + hf[4]*wa1.x + hf[5]*wa1.y + hf[6]*wa1.z + hf[7]*wa1.w;
            l1 += hf[0]*wb0.x + hf[1]*wb0.y + hf[2]*wb0.z + hf[3]*wb0.w
                + hf[4]*wb1.x + hf[5]*wb1.y + hf[6]*wb1.z + hf[7]*wb1.w;
        }
        l0 += __shfl_xor(l0, 1); l0 += __shfl_xor(l0, 2); l0 += __shfl_xor(l0, 4);
        l1 += __shfl_xor(l1, 1); l1 += __shfl_xor(l1, 2); l1 += __shfl_xor(l1, 4);
        const int eg = ebase + half * 64 + ml2;
        if (p == 0 && eg < NE) {
            l0 += b2[0]; l1 += b2[1];
            float mx = fmaxf(l0, l1);
            float e0 = expf(l0 - mx), e1 = expf(l1 - mx);
            float s = e0 + e1;
            float inv = 1.f / s;
            out[1 + 2 * eg] = e0 * inv;
            out[2 + 2 * eg] = e1 * inv;
            int lb = lab[eg];
            float w = cw[lb];
            float lpv = ((lb ? l1 : l0) - mx) - logf(s);
            wnll_t -= w * lpv;
            wsum_t += w;
        }
    }
    #pragma unroll
    for (int o = 1; o < 64; o <<= 1) {
        wnll_t += __shfl_xor(wnll_t, o);
        wsum_t += __shfl_xor(wsum_t, o);
    }
    __syncthreads();
    if (lane == 0) { red[wv] = wnll_t; red[8 + wv] = wsum_t; }
    __syncthreads();
    if (t == 0) {
        float a_ = 0.f, b_ = 0.f;
        #pragma unroll
        for (int i = 0; i < 8; ++i) { a_ += red[i]; b_ += red[8 + i]; }
        atomicAdd(&accum[0], a_);
        atomicAdd(&accum[1], b_);
    }
}

extern "C" void kernel_launch(void* const* d_in, const int* in_sizes, int n_in,
                              void* d_out, int out_size, void* d_ws, size_t ws_size,
                              hipStream_t stream)
{
    (void)in_sizes; (void)n_in; (void)out_size;
    const float* x  = (const float*)d_in[0];
    const float* W1 = (const float*)d_in[1];
    const float* b1 = (const float*)d_in[2];
    const float* W2 = (const float*)d_in[3];
    const float* b2 = (const float*)d_in[4];
    const float* cw = (const float*)d_in[5];
    const int* esrc = (const int*)d_in[6];
    const int* edst = (const int*)d_in[7];
    const int* lab  = (const int*)d_in[8];
    float* out = (float*)d_out;
    char* ws = (char*)d_ws;

    float* accum = (float*)ws;
    const size_t off_w1 = 256;
    const size_t w1s_bytes = (size_t)NOUT * HD * 2;      // 786432
    const size_t off_h = off_w1 + w1s_bytes;             // 786688 (16B aligned)
    const size_t h_bytes = (size_t)NN * NOUT * 2;        // 51.2 MB

    (void)hipMemsetAsync(accum, 0, 2 * sizeof(float), stream);

    if (ws_size >= off_h + h_bytes) {
        bf16_t* w1s = (bf16_t*)(ws + off_w1);
        f16_t* h = (f16_t*)(ws + off_h);
        int nsw = 2 * KST * 8 * 256;
        swz_w1_kernel<<<(nsw + 255) / 256, 256, 0, stream>>>(W1, w1s);
        int ngrid = ((NN + BM - 1) / BM) * 2;            // 782
        node_gemm<<<ngrid, 512, 0, stream>>>(x, w1s, h);
        edge_mlp2<<<NE / 16, 512, 0, stream>>>(h, b1, W2, b2, cw, esrc, edst, lab, out, accum);
    } else {
        dim3 grid((NE + BM - 1) / BM);
        fused_edge_mlp<false, false><<<grid, 512, 0, stream>>>(
            x, (const bf16_t*)ws, W1, (const bf16_t*)ws, b1, W2, b2, cw,
            esrc, edst, lab, out, accum);
    }

    finalize_kernel<<<1, 1, 0, stream>>>(out, accum);
}